// Round 1
// baseline (491.694 us; speedup 1.0000x reference)
//
#include <hip/hip_runtime.h>
#include <math.h>

#define D_MODEL 1024
#define DH 64
#define NH 16
#define BS 2
#define SEQ 2048
#define MTOT (BS*SEQ)   // 4096 rows

typedef _Float16 f16x8 __attribute__((ext_vector_type(8)));
typedef float f32x4 __attribute__((ext_vector_type(4)));

// ---------------------------------------------------------------------------
// QKV projection: C = X @ W^T + bias  (NT GEMM, fp32 in, f16 MFMA)
// grid = 24 col-blocks (8 per matrix q/k/v) x 32 row-blocks = 768 blocks
// Epilogue: q -> qh (b,h,n,d) f16 ; k -> present[0] fp32 + kh f16 ;
//           v -> present[1] fp32 + vt (b,h,d,n) f16 (transposed for PV-NT)
// ---------------------------------------------------------------------------
__global__ __launch_bounds__(256) void qkv_proj_kernel(
    const float* __restrict__ Xq, const float* __restrict__ Xk, const float* __restrict__ Xv,
    const float* __restrict__ Wq, const float* __restrict__ Wk, const float* __restrict__ Wv,
    const float* __restrict__ bq, const float* __restrict__ bk, const float* __restrict__ bv,
    _Float16* __restrict__ qh, _Float16* __restrict__ kh, _Float16* __restrict__ vt,
    float* __restrict__ outp)
{
    __shared__ __align__(16) _Float16 ldsA[128][40];   // pad 32->40 (bank spread)
    __shared__ __align__(16) _Float16 ldsB[128][40];

    const int jb = blockIdx.x >> 5;      // 0..23
    const int ib = blockIdx.x & 31;      // 0..31
    const int id = jb >> 3;              // 0:q 1:k 2:v (uniform per block)
    const int col0 = (jb & 7) << 7;
    const int row0 = ib << 7;

    const float* X    = (id == 0) ? Xq : (id == 1) ? Xk : Xv;
    const float* W    = (id == 0) ? Wq : (id == 1) ? Wk : Wv;
    const float* bias = (id == 0) ? bq : (id == 1) ? bk : bv;

    const int tid = threadIdx.x;
    const int w = tid >> 6, lane = tid & 63;
    const int quad = lane >> 4, l16 = lane & 15;
    const int wm = (w >> 1) << 6, wn = (w & 1) << 6;

    const f32x4 zero = {0.f, 0.f, 0.f, 0.f};
    f32x4 acc[4][4];
#pragma unroll
    for (int i = 0; i < 4; i++)
#pragma unroll
        for (int j = 0; j < 4; j++) acc[i][j] = zero;

    for (int k0 = 0; k0 < D_MODEL; k0 += 32) {
        __syncthreads();
#pragma unroll
        for (int i = 0; i < 4; i++) {          // 1024 float4 chunks / 256 thr
            int F = tid + 256 * i;
            int r = F >> 3, c4 = (F & 7) << 2;
            float4 va = *(const float4*)(X + (size_t)(row0 + r) * D_MODEL + k0 + c4);
            _Float16* pa = &ldsA[r][c4];
            pa[0] = (_Float16)va.x; pa[1] = (_Float16)va.y;
            pa[2] = (_Float16)va.z; pa[3] = (_Float16)va.w;
            float4 vb = *(const float4*)(W + (size_t)(col0 + r) * D_MODEL + k0 + c4);
            _Float16* pb = &ldsB[r][c4];
            pb[0] = (_Float16)vb.x; pb[1] = (_Float16)vb.y;
            pb[2] = (_Float16)vb.z; pb[3] = (_Float16)vb.w;
        }
        __syncthreads();
        f16x8 af[4], bfr[4];
#pragma unroll
        for (int mi = 0; mi < 4; mi++) af[mi]  = *(const f16x8*)&ldsA[wm + mi*16 + l16][quad*8];
#pragma unroll
        for (int ni = 0; ni < 4; ni++) bfr[ni] = *(const f16x8*)&ldsB[wn + ni*16 + l16][quad*8];
#pragma unroll
        for (int mi = 0; mi < 4; mi++)
#pragma unroll
            for (int ni = 0; ni < 4; ni++)
                acc[mi][ni] = __builtin_amdgcn_mfma_f32_16x16x32_f16(af[mi], bfr[ni], acc[mi][ni], 0, 0, 0);
    }

    const size_t OUT0 = (size_t)MTOT * D_MODEL;        // 4,194,304 (out region)
    const size_t PRES = (size_t)BS * NH * SEQ * DH;    // 4,194,304 (one k/v slab)
#pragma unroll
    for (int ni = 0; ni < 4; ni++) {
        int gn = col0 + wn + ni * 16 + l16;            // output feature 0..1023
        float bias_v = bias[gn];
        int h = gn >> 6, d = gn & 63;
#pragma unroll
        for (int mi = 0; mi < 4; mi++) {
#pragma unroll
            for (int r = 0; r < 4; r++) {
                int gm = row0 + wm + mi * 16 + quad * 4 + r;   // C: row=quad*4+reg
                float val = acc[mi][ni][r] + bias_v;
                int b = gm >> 11, n = gm & 2047;
                size_t bh = (size_t)(b * NH + h);
                size_t idx = (bh * SEQ + n) * DH + d;
                if (id == 0) {
                    qh[idx] = (_Float16)val;
                } else if (id == 1) {
                    outp[OUT0 + idx] = val;            // present[0][b][h][n][d]
                    kh[idx] = (_Float16)val;
                } else {
                    outp[OUT0 + PRES + idx] = val;     // present[1][b][h][n][d]
                    vt[(bh * DH + d) * SEQ + n] = (_Float16)val; // V^T (b,h,d,n)
                }
            }
        }
    }
}

// ---------------------------------------------------------------------------
// Flash-style attention with softmax-one: out = (sum e_j v_j) / (1 + sum e_j)
// 1 block = (b,h) x 64 q-rows; wave w owns 16 q-rows. S=2048 keys in tiles of 64.
// QK^T: NT mfma (Q rows x K rows). PV: NT mfma vs V^T. P transposed C->A layout
// via per-wave LDS round-trip (m120-verified pattern).
// ---------------------------------------------------------------------------
__global__ __launch_bounds__(256) void attn_kernel(
    const _Float16* __restrict__ qh, const _Float16* __restrict__ kh,
    const _Float16* __restrict__ vt, _Float16* __restrict__ aout)
{
    __shared__ __align__(16) _Float16 pbuf[4][16][72];   // per-wave, pad 64->72

    const int qt = blockIdx.x & 31;
    const int bh = blockIdx.x >> 5;
    const int b = bh >> 4, h = bh & 15;
    const int tid = threadIdx.x;
    const int w = tid >> 6, lane = tid & 63;
    const int quad = lane >> 4, l16 = lane & 15;
    const int qr0 = qt * 64 + w * 16;

    const _Float16* Qb = qh + (size_t)bh * SEQ * DH;
    const _Float16* Kb = kh + (size_t)bh * SEQ * DH;
    const _Float16* Vb = vt + (size_t)bh * DH * SEQ;

    f16x8 aq[2];
#pragma unroll
    for (int ks = 0; ks < 2; ks++)
        aq[ks] = *(const f16x8*)(Qb + (size_t)(qr0 + l16) * DH + ks * 32 + quad * 8);

    float mrun[4], lrun[4];
    const f32x4 zero = {0.f, 0.f, 0.f, 0.f};
    f32x4 accv[4];
#pragma unroll
    for (int r = 0; r < 4; r++) { mrun[r] = -INFINITY; lrun[r] = 0.f; }
#pragma unroll
    for (int db = 0; db < 4; db++) accv[db] = zero;

    for (int kc = 0; kc < SEQ; kc += 64) {
        f32x4 s[4];
#pragma unroll
        for (int nb = 0; nb < 4; nb++) s[nb] = zero;
#pragma unroll
        for (int ks = 0; ks < 2; ks++)
#pragma unroll
            for (int nb = 0; nb < 4; nb++) {
                f16x8 bk = *(const f16x8*)(Kb + (size_t)(kc + nb*16 + l16) * DH + ks*32 + quad*8);
                s[nb] = __builtin_amdgcn_mfma_f32_16x16x32_f16(aq[ks], bk, s[nb], 0, 0, 0);
            }
#pragma unroll
        for (int nb = 0; nb < 4; nb++)
#pragma unroll
            for (int r = 0; r < 4; r++) s[nb][r] *= 0.125f;    // 1/sqrt(64)

        float alpha[4];
#pragma unroll
        for (int r = 0; r < 4; r++) {
            float v0 = fmaxf(fmaxf(s[0][r], s[1][r]), fmaxf(s[2][r], s[3][r]));
#pragma unroll
            for (int off = 1; off < 16; off <<= 1) v0 = fmaxf(v0, __shfl_xor(v0, off));
            float mnew = fmaxf(mrun[r], v0);
            alpha[r] = __expf(mrun[r] - mnew);   // exp(-inf)=0 on first tile
            mrun[r] = mnew;
#pragma unroll
            for (int nb = 0; nb < 4; nb++) s[nb][r] = __expf(s[nb][r] - mnew);
            float t = (s[0][r] + s[1][r]) + (s[2][r] + s[3][r]);
#pragma unroll
            for (int off = 1; off < 16; off <<= 1) t += __shfl_xor(t, off);
            lrun[r] = lrun[r] * alpha[r] + t;
        }
#pragma unroll
        for (int db = 0; db < 4; db++)
#pragma unroll
            for (int r = 0; r < 4; r++) accv[db][r] *= alpha[r];

        // P: C-layout (row=quad*4+r, col=nb*16+l16) -> LDS -> A-layout read
#pragma unroll
        for (int nb = 0; nb < 4; nb++)
#pragma unroll
            for (int r = 0; r < 4; r++)
                pbuf[w][quad*4 + r][nb*16 + l16] = (_Float16)s[nb][r];
        __syncthreads();   // uniform; also forces LDS write->read ordering
        f16x8 ap[2];
#pragma unroll
        for (int ks = 0; ks < 2; ks++)
            ap[ks] = *(const f16x8*)&pbuf[w][l16][ks*32 + quad*8];
#pragma unroll
        for (int ks = 0; ks < 2; ks++)
#pragma unroll
            for (int db = 0; db < 4; db++) {
                f16x8 bv = *(const f16x8*)(Vb + (size_t)(db*16 + l16) * SEQ + kc + ks*32 + quad*8);
                accv[db] = __builtin_amdgcn_mfma_f32_16x16x32_f16(ap[ks], bv, accv[db], 0, 0, 0);
            }
    }

    // softmax-one divisor: 1 + l
#pragma unroll
    for (int db = 0; db < 4; db++)
#pragma unroll
        for (int r = 0; r < 4; r++) {
            float o = accv[db][r] / (1.f + lrun[r]);
            int row = qr0 + quad * 4 + r;
            aout[((size_t)b * SEQ + row) * D_MODEL + h * DH + db * 16 + l16] = (_Float16)o;
        }
}

// ---------------------------------------------------------------------------
// Output projection: out = attn(4096x1024 f16) @ Wo^T + bo  (NT GEMM)
// grid = 8 col-blocks x 32 row-blocks = 256 blocks
// ---------------------------------------------------------------------------
__global__ __launch_bounds__(256) void out_proj_kernel(
    const _Float16* __restrict__ aout, const float* __restrict__ Wo,
    const float* __restrict__ bo, float* __restrict__ outp)
{
    __shared__ __align__(16) _Float16 ldsA[128][40];
    __shared__ __align__(16) _Float16 ldsB[128][40];

    const int jb = blockIdx.x >> 5;   // 0..7
    const int ib = blockIdx.x & 31;
    const int col0 = jb << 7, row0 = ib << 7;
    const int tid = threadIdx.x;
    const int w = tid >> 6, lane = tid & 63;
    const int quad = lane >> 4, l16 = lane & 15;
    const int wm = (w >> 1) << 6, wn = (w & 1) << 6;

    const f32x4 zero = {0.f, 0.f, 0.f, 0.f};
    f32x4 acc[4][4];
#pragma unroll
    for (int i = 0; i < 4; i++)
#pragma unroll
        for (int j = 0; j < 4; j++) acc[i][j] = zero;

    for (int k0 = 0; k0 < D_MODEL; k0 += 32) {
        __syncthreads();
#pragma unroll
        for (int i = 0; i < 2; i++) {          // A already f16: 512 16B chunks
            int C = tid + 256 * i;
            int r = C >> 2, c8 = (C & 3) << 3;
            *(f16x8*)&ldsA[r][c8] = *(const f16x8*)(aout + (size_t)(row0 + r) * D_MODEL + k0 + c8);
        }
#pragma unroll
        for (int i = 0; i < 4; i++) {          // Wo fp32 -> f16
            int F = tid + 256 * i;
            int r = F >> 3, c4 = (F & 7) << 2;
            float4 vb = *(const float4*)(Wo + (size_t)(col0 + r) * D_MODEL + k0 + c4);
            _Float16* pb = &ldsB[r][c4];
            pb[0] = (_Float16)vb.x; pb[1] = (_Float16)vb.y;
            pb[2] = (_Float16)vb.z; pb[3] = (_Float16)vb.w;
        }
        __syncthreads();
        f16x8 af[4], bfr[4];
#pragma unroll
        for (int mi = 0; mi < 4; mi++) af[mi]  = *(const f16x8*)&ldsA[wm + mi*16 + l16][quad*8];
#pragma unroll
        for (int ni = 0; ni < 4; ni++) bfr[ni] = *(const f16x8*)&ldsB[wn + ni*16 + l16][quad*8];
#pragma unroll
        for (int mi = 0; mi < 4; mi++)
#pragma unroll
            for (int ni = 0; ni < 4; ni++)
                acc[mi][ni] = __builtin_amdgcn_mfma_f32_16x16x32_f16(af[mi], bfr[ni], acc[mi][ni], 0, 0, 0);
    }

#pragma unroll
    for (int ni = 0; ni < 4; ni++) {
        int gn = col0 + wn + ni * 16 + l16;
        float bias_v = bo[gn];
#pragma unroll
        for (int mi = 0; mi < 4; mi++)
#pragma unroll
            for (int r = 0; r < 4; r++) {
                int gm = row0 + wm + mi * 16 + quad * 4 + r;
                outp[(size_t)gm * D_MODEL + gn] = acc[mi][ni][r] + bias_v;
            }
    }
}

// ---------------------------------------------------------------------------
extern "C" void kernel_launch(void* const* d_in, const int* in_sizes, int n_in,
                              void* d_out, int out_size, void* d_ws, size_t ws_size,
                              hipStream_t stream)
{
    const float* queries = (const float*)d_in[0];
    const float* keys    = (const float*)d_in[1];
    const float* values  = (const float*)d_in[2];
    const float* Wq = (const float*)d_in[3];
    const float* bq = (const float*)d_in[4];
    const float* Wk = (const float*)d_in[5];
    const float* bk = (const float*)d_in[6];
    const float* Wv = (const float*)d_in[7];
    const float* bv = (const float*)d_in[8];
    const float* Wo = (const float*)d_in[9];
    const float* bo = (const float*)d_in[10];
    float* outp = (float*)d_out;

    // workspace: 4 x 8 MB f16 slabs = 32 MB
    const size_t NELT = (size_t)BS * NH * SEQ * DH;   // 4,194,304
    _Float16* qh   = (_Float16*)d_ws;                 // (b,h,n,d)
    _Float16* kh   = qh + NELT;                       // (b,h,n,d)
    _Float16* vt   = kh + NELT;                       // (b,h,d,n)  V^T
    _Float16* aout = vt + NELT;                       // (b,n,h*d)

    qkv_proj_kernel<<<dim3(768), dim3(256), 0, stream>>>(
        queries, keys, values, Wq, Wk, Wv, bq, bk, bv, qh, kh, vt, outp);
    attn_kernel<<<dim3(1024), dim3(256), 0, stream>>>(qh, kh, vt, aout);
    out_proj_kernel<<<dim3(256), dim3(256), 0, stream>>>(aout, Wo, bo, outp);
}